// Round 1
// baseline (245.557 us; speedup 1.0000x reference)
//
#include <hip/hip_runtime.h>
#include <math.h>

// loss = -sum_ij d1[i,j] * log(d2[i,j] + 1e-5), fp32 in, scalar fp32 out.
// Roofline: 134 MB demand -> ~21 us @ 6.3 TB/s (half is L3-resident, so
// potentially better).
//
// R3 theory: previous "2-deep pipeline" collapsed in codegen (VGPR_Count=24
// can't hold 8 live float4) -> <=2 dwordx4 in flight/wave -> latency-bound at
// 3.1 TB/s effective. Fix: pin an 8-load block per chunk with
// sched_barrier(0) so 8 KB/wave is in flight during compute, cap VGPR<=64 via
// __launch_bounds__(256,8) to keep 8 waves/SIMD. Also fuse the final
// reduction (atomic-counter last-block) to drop one dispatch from the timed
// region. Reduction order identical to the old two-kernel version (absmax 0).

#define EPS 1e-5f
#define BLOCK 256
#define GRID 2048     // 8 blocks/CU on 256 CUs -> whole grid co-resident
#define CHUNK 4       // float4 per array per load block (8 dwordx4 in flight)
#define CHUNKS 2      // 8 float4 per array per thread; GRID*BLOCK*8 == n4

__device__ __forceinline__ float block_reduce(float acc, float* wsum) {
    #pragma unroll
    for (int off = 32; off > 0; off >>= 1)
        acc += __shfl_down(acc, off, 64);
    int lane = threadIdx.x & 63;
    int wid  = threadIdx.x >> 6;
    if (lane == 0) wsum[wid] = acc;
    __syncthreads();
    return wsum[0] + wsum[1] + wsum[2] + wsum[3];  // only meaningful on t0-ish
}

__global__ __launch_bounds__(BLOCK, 8) void cep_fused_kernel(
        const float4* __restrict__ d1,
        const float4* __restrict__ d2,
        float* __restrict__ out,
        float* __restrict__ partials,
        unsigned int* __restrict__ counter) {
    const int tid    = blockIdx.x * BLOCK + threadIdx.x;
    const int stride = GRID * BLOCK;

    float acc0 = 0.0f, acc1 = 0.0f, acc2 = 0.0f, acc3 = 0.0f;

    int idx = tid;
    #pragma unroll
    for (int c = 0; c < CHUNKS; ++c) {
        float4 y[CHUNK], x[CHUNK];
        // Issue all 8 loads back-to-back: 8 dwordx4 = 8 KB in flight per wave.
        #pragma unroll
        for (int p = 0; p < CHUNK; ++p) y[p] = d2[idx + p * stride];
        #pragma unroll
        for (int p = 0; p < CHUNK; ++p) x[p] = d1[idx + p * stride];
        // Do not let the scheduler sink loads into the compute below.
        __builtin_amdgcn_sched_barrier(0);
        #pragma unroll
        for (int p = 0; p < CHUNK; ++p) {
            acc0 = fmaf(x[p].x, __logf(y[p].x + EPS), acc0);
            acc1 = fmaf(x[p].y, __logf(y[p].y + EPS), acc1);
            acc2 = fmaf(x[p].z, __logf(y[p].z + EPS), acc2);
            acc3 = fmaf(x[p].w, __logf(y[p].w + EPS), acc3);
        }
        idx += CHUNK * stride;
    }

    float acc = (acc0 + acc1) + (acc2 + acc3);

    __shared__ float wsum[BLOCK / 64];
    float bsum = block_reduce(acc, wsum);

    __shared__ bool amlast;
    if (threadIdx.x == 0) {
        partials[blockIdx.x] = bsum;
        // Release: make the partial visible agent-wide before the ticket.
        unsigned prev = __hip_atomic_fetch_add(counter, 1u,
                __ATOMIC_ACQ_REL, __HIP_MEMORY_SCOPE_AGENT);
        amlast = (prev == GRID - 1);
    }
    __syncthreads();
    if (!amlast) return;

    // Last block: deterministic final reduce, same order as the old
    // cep_final_kernel (thread t sums partials[t], t+256, ...).
    float facc = 0.0f;
    for (int i = threadIdx.x; i < GRID; i += BLOCK)
        facc += __hip_atomic_load(&partials[i],
                __ATOMIC_RELAXED, __HIP_MEMORY_SCOPE_AGENT);
    __syncthreads();  // wsum reuse hazard
    float fsum = block_reduce(facc, wsum);
    if (threadIdx.x == 0) out[0] = -fsum;
}

// ---- fallback two-kernel path (only if workspace is too small) ----

__global__ __launch_bounds__(BLOCK) void cep_loss_kernel(
        const float4* __restrict__ d1,
        const float4* __restrict__ d2,
        float* __restrict__ partials) {
    const int tid    = blockIdx.x * BLOCK + threadIdx.x;
    const int stride = GRID * BLOCK;
    float acc0 = 0.0f, acc1 = 0.0f, acc2 = 0.0f, acc3 = 0.0f;
    int idx = tid;
    #pragma unroll
    for (int c = 0; c < CHUNKS; ++c) {
        float4 y[CHUNK], x[CHUNK];
        #pragma unroll
        for (int p = 0; p < CHUNK; ++p) y[p] = d2[idx + p * stride];
        #pragma unroll
        for (int p = 0; p < CHUNK; ++p) x[p] = d1[idx + p * stride];
        __builtin_amdgcn_sched_barrier(0);
        #pragma unroll
        for (int p = 0; p < CHUNK; ++p) {
            acc0 = fmaf(x[p].x, __logf(y[p].x + EPS), acc0);
            acc1 = fmaf(x[p].y, __logf(y[p].y + EPS), acc1);
            acc2 = fmaf(x[p].z, __logf(y[p].z + EPS), acc2);
            acc3 = fmaf(x[p].w, __logf(y[p].w + EPS), acc3);
        }
        idx += CHUNK * stride;
    }
    float acc = (acc0 + acc1) + (acc2 + acc3);
    __shared__ float wsum[BLOCK / 64];
    float bsum = block_reduce(acc, wsum);
    if (threadIdx.x == 0) partials[blockIdx.x] = bsum;
}

__global__ __launch_bounds__(BLOCK) void cep_final_kernel(
        const float* __restrict__ partials, float* __restrict__ out) {
    float acc = 0.0f;
    for (int i = threadIdx.x; i < GRID; i += BLOCK)
        acc += partials[i];
    __shared__ float wsum[BLOCK / 64];
    float fsum = block_reduce(acc, wsum);
    if (threadIdx.x == 0) out[0] = -fsum;
}

extern "C" void kernel_launch(void* const* d_in, const int* in_sizes, int n_in,
                              void* d_out, int out_size, void* d_ws, size_t ws_size,
                              hipStream_t stream) {
    const float4* d1 = (const float4*)d_in[0];
    const float4* d2 = (const float4*)d_in[1];
    float* out      = (float*)d_out;
    float* partials = (float*)d_ws;

    const size_t need = (size_t)GRID * sizeof(float) + sizeof(unsigned int);
    if (ws_size >= need) {
        unsigned int* counter = (unsigned int*)((char*)d_ws + GRID * sizeof(float));
        hipMemsetAsync(counter, 0, sizeof(unsigned int), stream);  // graph-capturable
        cep_fused_kernel<<<GRID, BLOCK, 0, stream>>>(d1, d2, out, partials, counter);
    } else {
        cep_loss_kernel<<<GRID, BLOCK, 0, stream>>>(d1, d2, partials);
        cep_final_kernel<<<1, BLOCK, 0, stream>>>(partials, out);
    }
}

// Round 2
// 147.129 us; speedup vs baseline: 1.6690x; 1.6690x over previous
//
#include <hip/hip_runtime.h>
#include <math.h>

// loss = -sum_ij d1[i,j] * log(d2[i,j] + 1e-5), fp32 in, scalar fp32 out.
// Roofline: 134 MB demand -> ~21 us @ 6.3 TB/s (part L3-resident -> less).
//
// R1 post-mortem: last-block fusion with agent-scope ACQ_REL atomics caused
// per-block L2 writeback/invalidate storms (gfx950 XCD L2s non-coherent) ->
// 147 us. Reverted to two dispatches.
// R2: the latency fix must be forced via inline asm: the machine scheduler
// always collapses C-level load batches to load->use pairs (VGPR 24/28 both
// rounds). Rolling 4-pair software pipeline: 8 dwordx4 (8 KB/wave) in flight
// continuously, hand-counted s_waitcnt vmcnt(N) + sched_barrier(0) (rule:
// compiler will NOT insert waits for asm loads, and register-only ops can
// float past an asm waitcnt without the sched_barrier).
// Element->accumulator mapping and reduction tree kept bitwise identical to
// the 43 us baseline (absmax 0.0 preserved).

#define EPS 1e-5f
#define BLOCK 256
#define GRID 2048                 // 8 blocks/CU -> whole grid co-resident
#define STRIDE (GRID * BLOCK)     // 524288 float4; thread t owns t + p*STRIDE, p=0..7

typedef float f4v __attribute__((ext_vector_type(4)));

// Two ordered loads (one per array). Volatile asm blocks keep program order
// among themselves -> back-to-back issue, no scheduler collapse.
#define LOAD2(Y, X, PB, PA)                                   \
    asm volatile("global_load_dwordx4 %0, %2, off\n\t"        \
                 "global_load_dwordx4 %1, %3, off"            \
                 : "=&v"(Y), "=&v"(X)                         \
                 : "v"(PB), "v"(PA)                           \
                 : "memory")

// Hand-counted wait + scheduling fence (rule #18: without the sched_barrier,
// hipcc may hoist register-only consumers above the asm waitcnt).
#define WAITV(N)                                              \
    do {                                                      \
        asm volatile("s_waitcnt vmcnt(" #N ")" ::: "memory"); \
        __builtin_amdgcn_sched_barrier(0);                    \
    } while (0)

// Same element->acc mapping and fma contraction as the 43 us baseline.
#define CP(X, Y)                                              \
    do {                                                      \
        acc0 = fmaf((X).x, __logf((Y).x + EPS), acc0);        \
        acc1 = fmaf((X).y, __logf((Y).y + EPS), acc1);        \
        acc2 = fmaf((X).z, __logf((Y).z + EPS), acc2);        \
        acc3 = fmaf((X).w, __logf((Y).w + EPS), acc3);        \
    } while (0)

__global__ __launch_bounds__(BLOCK) void cep_loss_kernel(
        const f4v* __restrict__ d1,
        const f4v* __restrict__ d2,
        float* __restrict__ partials) {
    const int tid = blockIdx.x * BLOCK + threadIdx.x;
    const f4v* pa = d1 + tid;
    const f4v* pb = d2 + tid;

    float acc0 = 0.0f, acc1 = 0.0f, acc2 = 0.0f, acc3 = 0.0f;

    f4v x0, x1, x2, x3, x4, x5, x6, x7;
    f4v y0, y1, y2, y3, y4, y5, y6, y7;

    // Prologue: fill pipeline 4 pairs deep (8 dwordx4 = 8 KB/wave in flight).
    LOAD2(y0, x0, pb, pa); pb += STRIDE; pa += STRIDE;
    LOAD2(y1, x1, pb, pa); pb += STRIDE; pa += STRIDE;
    LOAD2(y2, x2, pb, pa); pb += STRIDE; pa += STRIDE;
    LOAD2(y3, x3, pb, pa); pb += STRIDE; pa += STRIDE;

    // Steady state: wait for oldest pair, refill, compute. In-flight never
    // drops below 3 pairs until the tail.
    WAITV(6); LOAD2(y4, x4, pb, pa); pb += STRIDE; pa += STRIDE; CP(x0, y0);
    WAITV(6); LOAD2(y5, x5, pb, pa); pb += STRIDE; pa += STRIDE; CP(x1, y1);
    WAITV(6); LOAD2(y6, x6, pb, pa); pb += STRIDE; pa += STRIDE; CP(x2, y2);
    WAITV(6); LOAD2(y7, x7, pb, pa);                             CP(x3, y3);

    // Drain.
    WAITV(6); CP(x4, y4);
    WAITV(4); CP(x5, y5);
    WAITV(2); CP(x6, y6);
    WAITV(0); CP(x7, y7);

    float acc = (acc0 + acc1) + (acc2 + acc3);

    // Wave-64 shuffle reduction (identical tree to baseline).
    #pragma unroll
    for (int off = 32; off > 0; off >>= 1)
        acc += __shfl_down(acc, off, 64);

    __shared__ float wave_sums[BLOCK / 64];
    int lane = threadIdx.x & 63;
    int wid  = threadIdx.x >> 6;
    if (lane == 0) wave_sums[wid] = acc;
    __syncthreads();

    if (threadIdx.x == 0) {
        float s = wave_sums[0] + wave_sums[1] + wave_sums[2] + wave_sums[3];
        partials[blockIdx.x] = s;  // deterministic: no atomics
    }
}

__global__ __launch_bounds__(BLOCK) void cep_final_kernel(
        const float* __restrict__ partials, float* __restrict__ out, int nparts) {
    float acc = 0.0f;
    for (int i = threadIdx.x; i < nparts; i += BLOCK)
        acc += partials[i];

    #pragma unroll
    for (int off = 32; off > 0; off >>= 1)
        acc += __shfl_down(acc, off, 64);

    __shared__ float wave_sums[BLOCK / 64];
    int lane = threadIdx.x & 63;
    int wid  = threadIdx.x >> 6;
    if (lane == 0) wave_sums[wid] = acc;
    __syncthreads();

    if (threadIdx.x == 0) {
        float s = wave_sums[0] + wave_sums[1] + wave_sums[2] + wave_sums[3];
        out[0] = -s;
    }
}

extern "C" void kernel_launch(void* const* d_in, const int* in_sizes, int n_in,
                              void* d_out, int out_size, void* d_ws, size_t ws_size,
                              hipStream_t stream) {
    const f4v* d1 = (const f4v*)d_in[0];
    const f4v* d2 = (const f4v*)d_in[1];
    float* out      = (float*)d_out;
    float* partials = (float*)d_ws;

    // n = 4096*4096 = 16,777,216 floats -> n4 = 4,194,304 float4.
    // GRID * BLOCK * 8 == n4 exactly.
    cep_loss_kernel<<<GRID, BLOCK, 0, stream>>>(d1, d2, partials);
    cep_final_kernel<<<1, BLOCK, 0, stream>>>(partials, out, GRID);
}

// Round 3
// 139.709 us; speedup vs baseline: 1.7576x; 1.0531x over previous
//
#include <hip/hip_runtime.h>
#include <math.h>

// loss = -sum_ij d1[i,j] * log(d2[i,j] + 1e-5), fp32 in, scalar fp32 out.
//
// R2 post-mortem: forced 8-deep asm pipeline (VGPR 32, 8 KB/wave in flight)
// changed NOTHING (44.9 vs 43.3 us) -> NOT latency/MLP-bound. Effective BW
// pinned at 3.05-3.15 TB/s across 3 structurally different kernels.
// FETCH=65.5 MB (= one array, true HBM) + ~68 MB L3-hit, each stream at
// ~1.55 TB/s in parallel.
// R3 experiment: force cache policy on the loads (sc0 sc1 nt = L2 bypass +
// non-temporal / no-allocate hint to the memory-side cache). Discriminates:
//   H1 (chip read-path ceiling ~3.15 TB/s, cf. 6.29 TB/s copy = 3.15r+3.15w)
//       -> FETCH doubles, dur unchanged -> roofline.
//   H2 (L3-hit/HBM-miss stream mixing is the pathology)
//       -> uniform HBM source, dur -> 24-32 us.
// Reduction tree (thread->window mapping, GRID/BLOCK, partials order) is
// FROZEN across rounds - absmax 0.0 must be preserved.

#define EPS 1e-5f
#define BLOCK 256
#define GRID 2048                 // 8 blocks/CU -> whole grid co-resident
#define STRIDE (GRID * BLOCK)     // 524288 float4; thread t owns t + p*STRIDE, p=0..7

typedef float f4v __attribute__((ext_vector_type(4)));

// Two ordered loads (one per array), L2-bypass + non-temporal.
#define LOAD2(Y, X, PB, PA)                                          \
    asm volatile("global_load_dwordx4 %0, %2, off sc0 sc1 nt\n\t"    \
                 "global_load_dwordx4 %1, %3, off sc0 sc1 nt"        \
                 : "=&v"(Y), "=&v"(X)                                \
                 : "v"(PB), "v"(PA)                                  \
                 : "memory")

// Hand-counted wait + scheduling fence (rule #18).
#define WAITV(N)                                              \
    do {                                                      \
        asm volatile("s_waitcnt vmcnt(" #N ")" ::: "memory"); \
        __builtin_amdgcn_sched_barrier(0);                    \
    } while (0)

// Same element->acc mapping and fma contraction as the 43 us baseline.
#define CP(X, Y)                                              \
    do {                                                      \
        acc0 = fmaf((X).x, __logf((Y).x + EPS), acc0);        \
        acc1 = fmaf((X).y, __logf((Y).y + EPS), acc1);        \
        acc2 = fmaf((X).z, __logf((Y).z + EPS), acc2);        \
        acc3 = fmaf((X).w, __logf((Y).w + EPS), acc3);        \
    } while (0)

__global__ __launch_bounds__(BLOCK) void cep_loss_kernel(
        const f4v* __restrict__ d1,
        const f4v* __restrict__ d2,
        float* __restrict__ partials) {
    const int tid = blockIdx.x * BLOCK + threadIdx.x;
    const f4v* pa = d1 + tid;
    const f4v* pb = d2 + tid;

    float acc0 = 0.0f, acc1 = 0.0f, acc2 = 0.0f, acc3 = 0.0f;

    f4v x0, x1, x2, x3, x4, x5, x6, x7;
    f4v y0, y1, y2, y3, y4, y5, y6, y7;

    // Prologue: fill pipeline 4 pairs deep (8 dwordx4 = 8 KB/wave in flight).
    LOAD2(y0, x0, pb, pa); pb += STRIDE; pa += STRIDE;
    LOAD2(y1, x1, pb, pa); pb += STRIDE; pa += STRIDE;
    LOAD2(y2, x2, pb, pa); pb += STRIDE; pa += STRIDE;
    LOAD2(y3, x3, pb, pa); pb += STRIDE; pa += STRIDE;

    // Steady state: wait for oldest pair, refill, compute.
    WAITV(6); LOAD2(y4, x4, pb, pa); pb += STRIDE; pa += STRIDE; CP(x0, y0);
    WAITV(6); LOAD2(y5, x5, pb, pa); pb += STRIDE; pa += STRIDE; CP(x1, y1);
    WAITV(6); LOAD2(y6, x6, pb, pa); pb += STRIDE; pa += STRIDE; CP(x2, y2);
    WAITV(6); LOAD2(y7, x7, pb, pa);                             CP(x3, y3);

    // Drain.
    WAITV(6); CP(x4, y4);
    WAITV(4); CP(x5, y5);
    WAITV(2); CP(x6, y6);
    WAITV(0); CP(x7, y7);

    float acc = (acc0 + acc1) + (acc2 + acc3);

    // Wave-64 shuffle reduction (identical tree to baseline).
    #pragma unroll
    for (int off = 32; off > 0; off >>= 1)
        acc += __shfl_down(acc, off, 64);

    __shared__ float wave_sums[BLOCK / 64];
    int lane = threadIdx.x & 63;
    int wid  = threadIdx.x >> 6;
    if (lane == 0) wave_sums[wid] = acc;
    __syncthreads();

    if (threadIdx.x == 0) {
        float s = wave_sums[0] + wave_sums[1] + wave_sums[2] + wave_sums[3];
        partials[blockIdx.x] = s;  // deterministic: no atomics
    }
}

__global__ __launch_bounds__(BLOCK) void cep_final_kernel(
        const float* __restrict__ partials, float* __restrict__ out, int nparts) {
    float acc = 0.0f;
    for (int i = threadIdx.x; i < nparts; i += BLOCK)
        acc += partials[i];

    #pragma unroll
    for (int off = 32; off > 0; off >>= 1)
        acc += __shfl_down(acc, off, 64);

    __shared__ float wave_sums[BLOCK / 64];
    int lane = threadIdx.x & 63;
    int wid  = threadIdx.x >> 6;
    if (lane == 0) wave_sums[wid] = acc;
    __syncthreads();

    if (threadIdx.x == 0) {
        float s = wave_sums[0] + wave_sums[1] + wave_sums[2] + wave_sums[3];
        out[0] = -s;
    }
}

extern "C" void kernel_launch(void* const* d_in, const int* in_sizes, int n_in,
                              void* d_out, int out_size, void* d_ws, size_t ws_size,
                              hipStream_t stream) {
    const f4v* d1 = (const f4v*)d_in[0];
    const f4v* d2 = (const f4v*)d_in[1];
    float* out      = (float*)d_out;
    float* partials = (float*)d_ws;

    // n = 4096*4096 floats -> n4 = 4,194,304 float4. GRID*BLOCK*8 == n4.
    cep_loss_kernel<<<GRID, BLOCK, 0, stream>>>(d1, d2, partials);
    cep_final_kernel<<<1, BLOCK, 0, stream>>>(partials, out, GRID);
}

// Round 4
// 132.893 us; speedup vs baseline: 1.8478x; 1.0513x over previous
//
#include <hip/hip_runtime.h>
#include <math.h>

// loss = -sum_ij d1[i,j] * log(d2[i,j] + 1e-5), fp32 in, scalar fp32 out.
//
// Session model (R0-R3):
//  - Reduction tree FROZEN (absmax 0.0): thread t owns elements t + p*STRIDE,
//    p=0..7, acc by component, wave shuffle, 4-wave LDS combine, partials[blk].
//  - R2: 8-deep forced pipeline changed nothing -> not software-MLP-bound.
//  - R3: sc0 sc1 nt = -16% (44.9 -> ~37.7 us). Mechanism: harness re-poison
//    leaves d1/d2 DIRTY in L3; allocate-on-read evicted dirty lines -> 64 MB
//    of concurrent HBM writeback (visible as WRITE_SIZE on a read-only
//    kernel). nt kills the cascade.
//  - Fill dispatches prove 6.6 TB/s single-direction; read-only pinned at
//    ~3.56 TB/s -> suspected per-CU outstanding-read tracking cap on the
//    VGPR-return path.
// R4 experiment: split the two streams across the chip's TWO read-return
// paths: d2 via global_load_lds (TA->LDS direct, separate return path),
// d1 via nt VGPR loads. Hand-counted vmcnt covers both (shared counter,
// 2 ops/stage). Per-wave-private LDS slots -> no barriers; lgkmcnt(0)
// before each ring-buffer reuse.

#define EPS 1e-5f
#define BLOCK 256
#define GRID 2048                 // 8 blocks/CU -> whole grid co-resident
#define STRIDE (GRID * BLOCK)     // float4 stride between a thread's windows

typedef float f4v __attribute__((ext_vector_type(4)));

#define AS1 __attribute__((address_space(1)))
#define AS3 __attribute__((address_space(3)))

// d1 load on the VGPR-return path, L2-bypass + non-temporal.
#define LOADX(X, PA)                                                 \
    asm volatile("global_load_dwordx4 %0, %1, off sc0 sc1 nt"        \
                 : "=&v"(X) : "v"(PA) : "memory")

// Hand-counted vmem wait + scheduling fence (rule #18).
#define WAITV(N)                                              \
    do {                                                      \
        asm volatile("s_waitcnt vmcnt(" #N ")" ::: "memory"); \
        __builtin_amdgcn_sched_barrier(0);                    \
    } while (0)

// Drain LDS reads before ring-slot reuse.
#define WAITLGKM()                                              \
    do {                                                        \
        asm volatile("s_waitcnt lgkmcnt(0)" ::: "memory");      \
        __builtin_amdgcn_sched_barrier(0);                      \
    } while (0)

// Same element->acc mapping and fma contraction as the 43 us baseline.
#define CP(X, Y)                                              \
    do {                                                      \
        acc0 = fmaf((X).x, __logf((Y).x + EPS), acc0);        \
        acc1 = fmaf((X).y, __logf((Y).y + EPS), acc1);        \
        acc2 = fmaf((X).z, __logf((Y).z + EPS), acc2);        \
        acc3 = fmaf((X).w, __logf((Y).w + EPS), acc3);        \
    } while (0)

__global__ __launch_bounds__(BLOCK) void cep_loss_kernel(
        const f4v* __restrict__ d1,
        const f4v* __restrict__ d2,
        float* __restrict__ partials) {
    // 4-deep ring of per-block staging buffers: 4 x 256 x 16B = 16 KB/block
    // -> 8 blocks/CU x 16 KB = 128 KB <= 160 KB LDS.
    __shared__ f4v sB[4][BLOCK];

    const int tid = blockIdx.x * BLOCK + threadIdx.x;
    const int wb  = threadIdx.x & ~63;   // wave-uniform slot base (lane 0)
    const f4v* pa = d1 + tid;
    const f4v* pb = d2 + tid;

    float acc0 = 0.0f, acc1 = 0.0f, acc2 = 0.0f, acc3 = 0.0f;
    f4v x0, x1, x2, x3, x4, x5, x6, x7;

    // One stage issue: d2 -> LDS-direct (wave-uniform dest base, HW adds
    // lane*16; per-lane GLOBAL src address), d1 -> VGPR path. 2 vmcnt ops.
#define ISSUE(BUF, X)                                                    \
    do {                                                                 \
        __builtin_amdgcn_global_load_lds(                                \
            (const AS1 void*)pb, (AS3 void*)&sB[BUF][wb], 16, 0, 0);     \
        LOADX(X, pa);                                                    \
        pb += STRIDE; pa += STRIDE;                                      \
    } while (0)

    // Prologue: 4 stages in flight (vmcnt = 8).
    ISSUE(0, x0); ISSUE(1, x1); ISSUE(2, x2); ISSUE(3, x3);

    f4v y;
    // Steady state: wait oldest stage (2 ops), read its LDS slice (this
    // wave's own slot - no cross-wave sharing, no barrier), drain the
    // ds_read (lgkmcnt) before reusing the slot, refill, compute.
    WAITV(6); y = sB[0][threadIdx.x]; WAITLGKM(); ISSUE(0, x4); CP(x0, y);
    WAITV(6); y = sB[1][threadIdx.x]; WAITLGKM(); ISSUE(1, x5); CP(x1, y);
    WAITV(6); y = sB[2][threadIdx.x]; WAITLGKM(); ISSUE(2, x6); CP(x2, y);
    WAITV(6); y = sB[3][threadIdx.x]; WAITLGKM(); ISSUE(3, x7); CP(x3, y);
    // Drain: stages 4..7 outstanding = 8,6,4,2 ops before each wait.
    WAITV(6); y = sB[0][threadIdx.x]; CP(x4, y);
    WAITV(4); y = sB[1][threadIdx.x]; CP(x5, y);
    WAITV(2); y = sB[2][threadIdx.x]; CP(x6, y);
    WAITV(0); y = sB[3][threadIdx.x]; CP(x7, y);

    float acc = (acc0 + acc1) + (acc2 + acc3);

    // Wave-64 shuffle reduction (identical tree to baseline).
    #pragma unroll
    for (int off = 32; off > 0; off >>= 1)
        acc += __shfl_down(acc, off, 64);

    __shared__ float wave_sums[BLOCK / 64];
    int lane = threadIdx.x & 63;
    int wid  = threadIdx.x >> 6;
    if (lane == 0) wave_sums[wid] = acc;
    __syncthreads();

    if (threadIdx.x == 0) {
        float s = wave_sums[0] + wave_sums[1] + wave_sums[2] + wave_sums[3];
        partials[blockIdx.x] = s;  // deterministic: no atomics
    }
}

__global__ __launch_bounds__(BLOCK) void cep_final_kernel(
        const float* __restrict__ partials, float* __restrict__ out, int nparts) {
    float acc = 0.0f;
    for (int i = threadIdx.x; i < nparts; i += BLOCK)
        acc += partials[i];

    #pragma unroll
    for (int off = 32; off > 0; off >>= 1)
        acc += __shfl_down(acc, off, 64);

    __shared__ float wave_sums[BLOCK / 64];
    int lane = threadIdx.x & 63;
    int wid  = threadIdx.x >> 6;
    if (lane == 0) wave_sums[wid] = acc;
    __syncthreads();

    if (threadIdx.x == 0) {
        float s = wave_sums[0] + wave_sums[1] + wave_sums[2] + wave_sums[3];
        out[0] = -s;
    }
}

extern "C" void kernel_launch(void* const* d_in, const int* in_sizes, int n_in,
                              void* d_out, int out_size, void* d_ws, size_t ws_size,
                              hipStream_t stream) {
    const f4v* d1 = (const f4v*)d_in[0];
    const f4v* d2 = (const f4v*)d_in[1];
    float* out      = (float*)d_out;
    float* partials = (float*)d_ws;

    // n = 4096*4096 floats -> n4 = 4,194,304 float4. GRID*BLOCK*8 == n4.
    cep_loss_kernel<<<GRID, BLOCK, 0, stream>>>(d1, d2, partials);
    cep_final_kernel<<<1, BLOCK, 0, stream>>>(partials, out, GRID);
}